// Round 11
// baseline (145.014 us; speedup 1.0000x reference)
//
#include <hip/hip_runtime.h>
#include <hip/hip_bf16.h>

// MLA-absorbed latent attention (round 11).
// r10 post-mortem: occupancy lever neutral => kernels ~93us of the 139.5
// (fills ~46us in timed window). This round: arithmetic-backed micro-opts:
// attn causal-mask hoist (diag tile only), BK=128 in both GEMMs (halve
// barrier drains), prep wq-arm LDS-staged (coalesced). Math order identical.

typedef __bf16 bf16_t;
typedef bf16_t bf16x8 __attribute__((ext_vector_type(8)));
typedef float f32x4 __attribute__((ext_vector_type(4)));

__device__ inline bf16x8 cvt8(const float* __restrict__ p) {
  f32x4 a = *(const f32x4*)p, b = *(const f32x4*)(p + 4);
  bf16x8 r;
#pragma unroll
  for (int i = 0; i < 4; ++i) { r[i] = (bf16_t)a[i]; r[4 + i] = (bf16_t)b[i]; }
  return r;
}

// ---- one-shot weight prep, all-MFMA, emits bf16 transposed weights ----
__global__ __launch_bounds__(256) void prep_mfma(
    const float* __restrict__ wq, const float* __restrict__ wkd,
    const float* __restrict__ wvd, const float* __restrict__ wku,
    const float* __restrict__ wvu, const float* __restrict__ wo,
    bf16_t* __restrict__ WqkvT, bf16_t* __restrict__ WcombT) {
  __shared__ __align__(16) char smem[34816];
  const int tid = threadIdx.x;
  const int wave = tid >> 6, lane = tid & 63;
  const int quad = lane >> 4, col = lane & 15;
  const int bi = blockIdx.x;

  if (bi < 64) { // wq_eff^T[32h+l][c] = sum_d wku[l][d]*wq[c][128h+d]
    const int h = bi >> 3;
    const int c0 = (bi & 7) * 128;
    // stage wq[c0..c0+127][h*128..h*128+127] -> LDS [c][d], coalesced rows
    bf16_t(*Wq)[136] = (bf16_t(*)[136])smem;
    {
      const int cc = tid >> 1, dseg = (tid & 1) * 64;
      const float* wp = wq + (size_t)(c0 + cc) * 1024 + h * 128 + dseg;
#pragma unroll
      for (int i = 0; i < 16; ++i) {
        f32x4 w4 = *(const f32x4*)(wp + i * 4);
#pragma unroll
        for (int t = 0; t < 4; ++t) Wq[cc][dseg + i * 4 + t] = (bf16_t)w4[t];
      }
    }
    __syncthreads();
    const int cw = wave * 32;
    f32x4 acc[2][2];
#pragma unroll
    for (int i = 0; i < 2; ++i)
#pragma unroll
      for (int j = 0; j < 2; ++j) acc[i][j] = (f32x4){0.f, 0.f, 0.f, 0.f};
#pragma unroll
    for (int ks = 0; ks < 4; ++ks) {
      const int ko = ks * 32 + quad * 8;
      bf16x8 a0 = cvt8(wku + col * 128 + ko);
      bf16x8 a1 = cvt8(wku + (16 + col) * 128 + ko);
      bf16x8 b0 = *(const bf16x8*)&Wq[cw + col][ko];
      bf16x8 b1 = *(const bf16x8*)&Wq[cw + 16 + col][ko];
      acc[0][0] = __builtin_amdgcn_mfma_f32_16x16x32_bf16(a0, b0, acc[0][0], 0, 0, 0);
      acc[0][1] = __builtin_amdgcn_mfma_f32_16x16x32_bf16(a0, b1, acc[0][1], 0, 0, 0);
      acc[1][0] = __builtin_amdgcn_mfma_f32_16x16x32_bf16(a1, b0, acc[1][0], 0, 0, 0);
      acc[1][1] = __builtin_amdgcn_mfma_f32_16x16x32_bf16(a1, b1, acc[1][1], 0, 0, 0);
    }
#pragma unroll
    for (int ms = 0; ms < 2; ++ms)
#pragma unroll
      for (int ns = 0; ns < 2; ++ns)
#pragma unroll
        for (int v = 0; v < 4; ++v)
          WqkvT[(size_t)(h * 32 + ms * 16 + quad * 4 + v) * 1024 + c0 + cw + ns * 16 + col] =
              (bf16_t)acc[ms][ns][v];
  } else if (bi < 128) { // WcombT[m][32h+l] = sum_d wvu[l][d]*wo[128h+d][m]
    const int b2 = bi - 64;
    const int h = b2 >> 3, m0 = (b2 & 7) * 128;
    bf16_t(*B_lds)[136] = (bf16_t(*)[136])smem; // [m][d]
    {
      const int d = tid >> 1, mh = (tid & 1) * 64;
      const float* wp = wo + (size_t)(h * 128 + d) * 1024 + m0 + mh;
#pragma unroll
      for (int i = 0; i < 16; ++i) {
        f32x4 w4 = *(const f32x4*)(wp + i * 4);
#pragma unroll
        for (int t = 0; t < 4; ++t) B_lds[mh + i * 4 + t][d] = (bf16_t)w4[t];
      }
    }
    __syncthreads();
    f32x4 acc[2][2];
#pragma unroll
    for (int i = 0; i < 2; ++i)
#pragma unroll
      for (int j = 0; j < 2; ++j) acc[i][j] = (f32x4){0.f, 0.f, 0.f, 0.f};
#pragma unroll
    for (int ks = 0; ks < 4; ++ks) {
      const int ko = ks * 32 + quad * 8;
      bf16x8 a0 = cvt8(wvu + col * 128 + ko);
      bf16x8 a1 = cvt8(wvu + (16 + col) * 128 + ko);
      bf16x8 b0 = *(const bf16x8*)&B_lds[wave * 32 + col][ko];
      bf16x8 b1 = *(const bf16x8*)&B_lds[wave * 32 + 16 + col][ko];
      acc[0][0] = __builtin_amdgcn_mfma_f32_16x16x32_bf16(a0, b0, acc[0][0], 0, 0, 0);
      acc[0][1] = __builtin_amdgcn_mfma_f32_16x16x32_bf16(a0, b1, acc[0][1], 0, 0, 0);
      acc[1][0] = __builtin_amdgcn_mfma_f32_16x16x32_bf16(a1, b0, acc[1][0], 0, 0, 0);
      acc[1][1] = __builtin_amdgcn_mfma_f32_16x16x32_bf16(a1, b1, acc[1][1], 0, 0, 0);
    }
#pragma unroll
    for (int ms = 0; ms < 2; ++ms)
#pragma unroll
      for (int ns = 0; ns < 2; ++ns)
#pragma unroll
        for (int v = 0; v < 4; ++v)
          WcombT[(size_t)(m0 + wave * 32 + ns * 16 + col) * 256 +
                 h * 32 + ms * 16 + quad * 4 + v] = (bf16_t)acc[ms][ns][v];
  } else { // wk_down/wv_down transpose into WqkvT rows 256..383
    const int b3 = bi - 128;
    const int mat = b3 >> 4, c0 = (b3 & 15) * 64;
    const float* in = mat ? wvd : wkd;
    bf16_t(*tT)[72] = (bf16_t(*)[72])smem;
    {
      const int cc = tid >> 2, jq = (tid & 3) * 16;
      const float* ip = in + (size_t)(c0 + cc) * 64 + jq;
#pragma unroll
      for (int q = 0; q < 4; ++q) {
        f32x4 v4 = *(const f32x4*)(ip + q * 4);
#pragma unroll
        for (int t = 0; t < 4; ++t) tT[jq + q * 4 + t][cc] = (bf16_t)v4[t];
      }
    }
    __syncthreads();
    {
      const int j = tid >> 2, cq = (tid & 3) * 16;
      bf16_t* op = WqkvT + (size_t)(256 + mat * 64 + j) * 1024 + c0 + cq;
      *(bf16x8*)op = *(const bf16x8*)&tT[j][cq];
      *(bf16x8*)(op + 8) = *(const bf16x8*)&tT[j][cq + 8];
    }
  }
}

// ---- QKV GEMM: C_bf16[4096][384] = A_f32[4096][1024] @ WqkvT_bf16[384][1024]^T ----
// BM=32 BN=128 BK=128 (8 iters, 16 barriers), grid (3,128)=384 blocks.
__global__ __launch_bounds__(256) void gemm_qkv(
    const float* __restrict__ A, const bf16_t* __restrict__ Bt,
    bf16_t* __restrict__ C) {
  __shared__ bf16_t As[32][136];
  __shared__ bf16_t Bs[128][136];
  const int tid = threadIdx.x;
  const int wave = tid >> 6, lane = tid & 63;
  const int quad = lane >> 4, col = lane & 15;
  const int wm = (wave >> 1) * 16, wn = (wave & 1) * 64;
  const int m0 = blockIdx.y * 32, n0 = blockIdx.x * 128;

  f32x4 acc[4];
#pragma unroll
  for (int j = 0; j < 4; ++j) acc[j] = (f32x4){0.f, 0.f, 0.f, 0.f};

  const int ar = tid >> 3, ac = (tid & 7) * 16;  // A: 32 rows x 128k, 16 f/thr
  const int br = tid >> 1, bc = (tid & 1) * 64;  // B: 128 rows x 128k, 64 bf/thr
  const float* aP = A + (size_t)(m0 + ar) * 1024 + ac;
  const bf16_t* bP = Bt + (size_t)(n0 + br) * 1024 + bc;

  bf16x8 aR[2], bR[8];
  aR[0] = cvt8(aP); aR[1] = cvt8(aP + 8);
#pragma unroll
  for (int t = 0; t < 8; ++t) bR[t] = *(const bf16x8*)(bP + t * 8);

  for (int kt = 0; kt < 8; ++kt) {
    *(bf16x8*)&As[ar][ac] = aR[0]; *(bf16x8*)&As[ar][ac + 8] = aR[1];
#pragma unroll
    for (int t = 0; t < 8; ++t) *(bf16x8*)&Bs[br][bc + t * 8] = bR[t];
    __syncthreads();
    if (kt < 7) {
      const int k0 = (kt + 1) * 128;
      aR[0] = cvt8(aP + k0); aR[1] = cvt8(aP + k0 + 8);
#pragma unroll
      for (int t = 0; t < 8; ++t) bR[t] = *(const bf16x8*)(bP + k0 + t * 8);
    }
#pragma unroll
    for (int ks = 0; ks < 4; ++ks) {
      bf16x8 af = *(const bf16x8*)&As[wm + col][ks * 32 + quad * 8];
      bf16x8 bfr[4];
#pragma unroll
      for (int j = 0; j < 4; ++j) bfr[j] = *(const bf16x8*)&Bs[wn + j * 16 + col][ks * 32 + quad * 8];
#pragma unroll
      for (int j = 0; j < 4; ++j)
        acc[j] = __builtin_amdgcn_mfma_f32_16x16x32_bf16(af, bfr[j], acc[j], 0, 0, 0);
    }
    __syncthreads();
  }

#pragma unroll
  for (int j = 0; j < 4; ++j) {
    const int cg = n0 + wn + j * 16 + col;
#pragma unroll
    for (int v = 0; v < 4; ++v)
      C[(size_t)(m0 + wm + quad * 4 + v) * 384 + cg] = (bf16_t)acc[j][v];
  }
}

// ---- out GEMM: C_f32[4096][1024] = A_bf16[4096][lda=384,K=256] @ WcombT_bf16[1024][256]^T ----
// BM=64 BN=128 BK=128 (2 iters, 4 barriers), grid (8,64)=512 blocks.
__global__ __launch_bounds__(256) void gemm_out(
    const bf16_t* __restrict__ A, const bf16_t* __restrict__ Bt,
    float* __restrict__ C) {
  __shared__ bf16_t As[64][136];
  __shared__ bf16_t Bs[128][136];
  const int tid = threadIdx.x;
  const int wave = tid >> 6, lane = tid & 63;
  const int quad = lane >> 4, col = lane & 15;
  const int wm = (wave >> 1) * 32, wn = (wave & 1) * 64;
  const int m0 = blockIdx.y * 64, n0 = blockIdx.x * 128;

  f32x4 acc[2][4];
#pragma unroll
  for (int i = 0; i < 2; ++i)
#pragma unroll
    for (int j = 0; j < 4; ++j) acc[i][j] = (f32x4){0.f, 0.f, 0.f, 0.f};

  const int ar = tid >> 2, ac = (tid & 3) * 32;  // A: 64 rows x 128k, 32 bf/thr
  const int br = tid >> 1, bc = (tid & 1) * 64;  // B: 128 rows x 128k, 64 bf/thr
  const bf16_t* aP = A + (size_t)(m0 + ar) * 384 + ac;
  const bf16_t* bP = Bt + (size_t)(n0 + br) * 256 + bc;

  bf16x8 aR[4], bR[8];
#pragma unroll
  for (int t = 0; t < 4; ++t) aR[t] = *(const bf16x8*)(aP + t * 8);
#pragma unroll
  for (int t = 0; t < 8; ++t) bR[t] = *(const bf16x8*)(bP + t * 8);

  for (int kt = 0; kt < 2; ++kt) {
#pragma unroll
    for (int t = 0; t < 4; ++t) *(bf16x8*)&As[ar][ac + t * 8] = aR[t];
#pragma unroll
    for (int t = 0; t < 8; ++t) *(bf16x8*)&Bs[br][bc + t * 8] = bR[t];
    __syncthreads();
    if (kt < 1) {
#pragma unroll
      for (int t = 0; t < 4; ++t) aR[t] = *(const bf16x8*)(aP + 128 + t * 8);
#pragma unroll
      for (int t = 0; t < 8; ++t) bR[t] = *(const bf16x8*)(bP + 128 + t * 8);
    }
#pragma unroll
    for (int ks = 0; ks < 4; ++ks) {
      bf16x8 af[2], bfr[4];
#pragma unroll
      for (int i = 0; i < 2; ++i) af[i] = *(const bf16x8*)&As[wm + i * 16 + col][ks * 32 + quad * 8];
#pragma unroll
      for (int j = 0; j < 4; ++j) bfr[j] = *(const bf16x8*)&Bs[wn + j * 16 + col][ks * 32 + quad * 8];
#pragma unroll
      for (int i = 0; i < 2; ++i)
#pragma unroll
        for (int j = 0; j < 4; ++j)
          acc[i][j] = __builtin_amdgcn_mfma_f32_16x16x32_bf16(af[i], bfr[j], acc[i][j], 0, 0, 0);
    }
    __syncthreads();
  }

#pragma unroll
  for (int i = 0; i < 2; ++i) {
    const int rg = m0 + wm + i * 16 + quad * 4;
#pragma unroll
    for (int j = 0; j < 4; ++j) {
      const int cg = n0 + wn + j * 16 + col;
#pragma unroll
      for (int v = 0; v < 4; ++v)
        C[(size_t)(rg + v) * 1024 + cg] = acc[i][j][v];
    }
  }
}

// ---- latent flash attention: balanced blocks, no-max softmax, K/V double
// buffer (1 barrier/tile), Ps same-wave, causal mask only on diagonal tile ----
__global__ __launch_bounds__(256) void attn_lat(bf16_t* QKV) {
  const int bi = blockIdx.x;
  const int half = bi >> 8, rest = bi & 255;
  const int qt = half ? 127 - (rest >> 1) : (rest >> 1);
  const int hkv = rest & 1, b = half;
  const int tid = threadIdx.x;
  const int wave = tid >> 6, lane = tid & 63;
  const int quad = lane >> 4, col = lane & 15;

  __shared__ bf16_t Ks[2][128][40];
  __shared__ bf16_t Vt[2][32][136];
  __shared__ bf16_t Ps[4][16][136];

  const int qb = qt * 16;
  const size_t rowbase = (size_t)b * 2048;
  const int qcol0 = (hkv * 4 + wave) * 32;

  bf16x8 a_q = *(const bf16x8*)(QKV + (rowbase + qb + col) * 384 + qcol0 + quad * 8);

  f32x4 o0 = (f32x4){0.f, 0.f, 0.f, 0.f};
  f32x4 o1 = (f32x4){0.f, 0.f, 0.f, 0.f};
  float lsum[4] = {0.f, 0.f, 0.f, 0.f};

  const int nkt = (qb >> 7) + 1;
  const float scale = 0.08838834764831843f; // 1/sqrt(128)

  const int kr = tid >> 1, dc = (tid & 1) * 16;
  const bf16_t* kvBase = QKV + (rowbase + kr) * 384 + 256 + hkv * 32 + dc;

  {
    bf16x8 kA = *(const bf16x8*)kvBase, kB = *(const bf16x8*)(kvBase + 8);
    bf16x8 vA = *(const bf16x8*)(kvBase + 64), vB = *(const bf16x8*)(kvBase + 72);
    *(bf16x8*)&Ks[0][kr][dc] = kA;
    *(bf16x8*)&Ks[0][kr][dc + 8] = kB;
#pragma unroll
    for (int t = 0; t < 8; ++t) { Vt[0][dc + t][kr] = vA[t]; Vt[0][dc + 8 + t][kr] = vB[t]; }
  }
  __syncthreads();

  for (int kt = 0; kt < nkt; ++kt) {
    const int cur = kt & 1;
    const int kb = kt * 128;
    const bool more = (kt + 1 < nkt);

    bf16x8 kA, kB, vA, vB;
    if (more) {
      const bf16_t* np = kvBase + (size_t)(kt + 1) * 128 * 384;
      kA = *(const bf16x8*)np; kB = *(const bf16x8*)(np + 8);
      vA = *(const bf16x8*)(np + 64); vB = *(const bf16x8*)(np + 72);
    }

    f32x4 s[8];
#pragma unroll
    for (int k8 = 0; k8 < 8; ++k8) {
      bf16x8 bk = *(const bf16x8*)&Ks[cur][k8 * 16 + col][quad * 8];
      s[k8] = __builtin_amdgcn_mfma_f32_16x16x32_bf16(a_q, bk, (f32x4){0.f, 0.f, 0.f, 0.f}, 0, 0, 0);
    }

    if (kb + 128 <= qb) { // full tile: no mask VALU at all
#pragma unroll
      for (int v = 0; v < 4; ++v) {
        const int qr = quad * 4 + v;
#pragma unroll
        for (int k8 = 0; k8 < 8; ++k8) {
          const float p = __expf(s[k8][v] * scale);
          lsum[v] += p;
          Ps[wave][qr][k8 * 16 + col] = (bf16_t)p;
        }
      }
    } else { // diagonal tile: causal mask
#pragma unroll
      for (int v = 0; v < 4; ++v) {
        const int qr = quad * 4 + v;
        const int qg = qb + qr;
#pragma unroll
        for (int k8 = 0; k8 < 8; ++k8) {
          float xx = (kb + k8 * 16 + col <= qg) ? s[k8][v] * scale : -1e30f;
          const float p = __expf(xx);
          lsum[v] += p;
          Ps[wave][qr][k8 * 16 + col] = (bf16_t)p;
        }
      }
    }
    __asm__ __volatile__("" ::: "memory"); // Ps: same-wave LDS, order only

#pragma unroll
    for (int kc = 0; kc < 4; ++kc) {
      bf16x8 a_p = *(const bf16x8*)&Ps[wave][col][kc * 32 + quad * 8];
      bf16x8 bv0 = *(const bf16x8*)&Vt[cur][col][kc * 32 + quad * 8];
      bf16x8 bv1 = *(const bf16x8*)&Vt[cur][16 + col][kc * 32 + quad * 8];
      o0 = __builtin_amdgcn_mfma_f32_16x16x32_bf16(a_p, bv0, o0, 0, 0, 0);
      o1 = __builtin_amdgcn_mfma_f32_16x16x32_bf16(a_p, bv1, o1, 0, 0, 0);
    }

    if (more) {
      *(bf16x8*)&Ks[cur ^ 1][kr][dc] = kA;
      *(bf16x8*)&Ks[cur ^ 1][kr][dc + 8] = kB;
#pragma unroll
      for (int t = 0; t < 8; ++t) { Vt[cur ^ 1][dc + t][kr] = vA[t]; Vt[cur ^ 1][dc + 8 + t][kr] = vB[t]; }
    }
    __syncthreads();
  }

#pragma unroll
  for (int v = 0; v < 4; ++v) {
    float l = lsum[v];
#pragma unroll
    for (int off = 8; off; off >>= 1) l += __shfl_xor(l, off, 64);
    const float inv = 1.f / l;
    const size_t r = (rowbase + qb + quad * 4 + v) * 384 + qcol0;
    QKV[r + col] = (bf16_t)(o0[v] * inv);
    QKV[r + 16 + col] = (bf16_t)(o1[v] * inv);
  }
}

// ---------------------------------------------------------------------------
extern "C" void kernel_launch(void* const* d_in, const int* in_sizes, int n_in,
                              void* d_out, int out_size, void* d_ws, size_t ws_size,
                              hipStream_t stream) {
  (void)in_sizes; (void)n_in; (void)out_size; (void)ws_size;
  const float* x   = (const float*)d_in[0];
  const float* wq  = (const float*)d_in[1];
  const float* wkd = (const float*)d_in[2];
  const float* wvd = (const float*)d_in[3];
  const float* wku = (const float*)d_in[4];
  const float* wvu = (const float*)d_in[5];
  const float* wo  = (const float*)d_in[6];
  float* out = (float*)d_out;

  // Workspace: 4.3 MB
  bf16_t* WqkvT  = (bf16_t*)d_ws;                 // [384][1024]
  bf16_t* WcombT = WqkvT + (size_t)384 * 1024;    // [1024][256]
  bf16_t* QKV    = WcombT + (size_t)1024 * 256;   // [4096][384]

  prep_mfma<<<160, 256, 0, stream>>>(wq, wkd, wvd, wku, wvu, wo, WqkvT, WcombT);
  gemm_qkv<<<dim3(3, 128), 256, 0, stream>>>(x, WqkvT, QKV);
  attn_lat<<<512, 256, 0, stream>>>(QKV);
  gemm_out<<<dim3(8, 64), 256, 0, stream>>>(QKV, WcombT, out);
}